// Round 7
// baseline (201.713 us; speedup 1.0000x reference)
//
#include <hip/hip_runtime.h>
#include <hip/hip_bf16.h>

// Problem constants (B,N,C,H,D,K) = (4, 8192, 384, 12, 2, 32)
#define B_  4
#define N_  8192
#define C_  384
#define H_  12
#define K_  32
#define M_  256          // N/K members per cluster
#define BN_ (B_*N_)      // 32768 rows
#define F2D 768          // 2*C
#define VSTR 260         // Vt row stride in elems (520B): 2-way on b64 reads (free)
#define LOG2E 1.4426950408889634f

typedef __attribute__((ext_vector_type(8)))  short  bf16x8;
typedef __attribute__((ext_vector_type(4)))  float  f32x4;
typedef __attribute__((ext_vector_type(16))) float  f32x16;
typedef __attribute__((ext_vector_type(4)))  ushort ushort4v;
typedef __attribute__((ext_vector_type(8)))  ushort ushort8v;

#define GLOBAL_AS __attribute__((address_space(1)))
#define LDS_AS    __attribute__((address_space(3)))

__device__ __forceinline__ void load_lds_16B(const ushort* g, ushort* l) {
    __builtin_amdgcn_global_load_lds((const GLOBAL_AS unsigned int*)g,
                                     (LDS_AS unsigned int*)l, 16, 0, 0);
}
__device__ __forceinline__ unsigned cvtpk_bf16(float lo, float hi) {
    unsigned r;
    asm("v_cvt_pk_bf16_f32 %0, %1, %2" : "=v"(r) : "v"(lo), "v"(hi));
    return r;
}

// ---------------------------------------------------------------- pos max
__global__ void posmax_kernel(const float* __restrict__ pos, unsigned* __restrict__ pmax) {
    int tid = blockIdx.x * blockDim.x + threadIdx.x;
    float m0 = 0.f, m1 = 0.f;
    for (int i = tid; i < BN_; i += gridDim.x * blockDim.x) {
        m0 = fmaxf(m0, pos[(size_t)i * 2 + 0]);
        m1 = fmaxf(m1, pos[(size_t)i * 2 + 1]);
    }
    #pragma unroll
    for (int off = 32; off; off >>= 1) {
        m0 = fmaxf(m0, __shfl_down(m0, off));
        m1 = fmaxf(m1, __shfl_down(m1, off));
    }
    __shared__ float s0[4], s1[4];
    int w = threadIdx.x >> 6;
    if ((threadIdx.x & 63) == 0) { s0[w] = m0; s1[w] = m1; }
    __syncthreads();
    if (threadIdx.x == 0) {
        for (int i = 1; i < 4; i++) { m0 = fmaxf(m0, s0[i]); m1 = fmaxf(m1, s1[i]); }
        atomicMax(&pmax[0], __float_as_uint(m0));   // pos >= 0: float order == uint order
        atomicMax(&pmax[1], __float_as_uint(m1));
    }
}

// ---------------------------------------------------------------- f32 -> bf16 cast
__global__ __launch_bounds__(256) void cast_kernel(const float* __restrict__ src,
                                                   ushort* __restrict__ dst, int n4) {
    int i = blockIdx.x * blockDim.x + threadIdx.x;
    if (i >= n4) return;
    float4 a = reinterpret_cast<const float4*>(src)[i];
    ushort4 o;
    __hip_bfloat16 h0 = __float2bfloat16(a.x); o.x = *(const ushort*)&h0;
    __hip_bfloat16 h1 = __float2bfloat16(a.y); o.y = *(const ushort*)&h1;
    __hip_bfloat16 h2 = __float2bfloat16(a.z); o.z = *(const ushort*)&h2;
    __hip_bfloat16 h3 = __float2bfloat16(a.w); o.w = *(const ushort*)&h3;
    reinterpret_cast<ushort4*>(dst)[i] = o;
}

// ---------------------------------------------------------------- gathered QKV GEMM
// One block per (bh, 128-member tile): A rows gathered by member_idx at stage time
// (latency hides in the MFMA pipeline). Output written dense in cluster order:
// q_g/k_g [bh][kcm][16], vt_g [bh][kc][64][256] (V transposed at the epilogue).
// LDS tiles XOR-swizzled (pre-swizzled global source, swizzled read) per T2.
__global__ __launch_bounds__(256) void gemm_qkv_g(const ushort* __restrict__ featb,
                                                  const ushort* __restrict__ wqkvb,
                                                  const float* __restrict__ bias,
                                                  const int* __restrict__ member_idx,
                                                  ushort* __restrict__ q_g,
                                                  ushort* __restrict__ k_g,
                                                  ushort* __restrict__ vt_g) {
    __shared__ ushort As[128 * 64];   // 16 KB, slot(row,kk) holds A[row][kk ^ swz(row)]
    __shared__ ushort Bs[96 * 64];    // 12 KB
    __shared__ int    miL[128];
    const int bh = blockIdx.y;              // 48
    const int bm = blockIdx.x * 128;        // member-tile base (single kc: 128 | 256)
    const int b  = bh / H_, h = bh % H_;
    const int t = threadIdx.x;
    const int l = t & 63;
    const int wr = (t >> 6) >> 1, wc = (t >> 6) & 1;
    const int fr = l & 15, fq = l >> 4;
    const size_t featrow = (size_t)b * N_;

    if (t < 128) miL[t] = member_idx[(size_t)bh * N_ + bm + t];
    __syncthreads();

    f32x4 zero = {0.f, 0.f, 0.f, 0.f};
    f32x4 acc[4][3];
    #pragma unroll
    for (int m = 0; m < 4; m++)
        #pragma unroll
        for (int n = 0; n < 3; n++) acc[m][n] = zero;

    for (int k0 = 0; k0 < 384; k0 += 64) {
        #pragma unroll
        for (int i = 0; i < 4; i++) {                 // A: 128x64, gathered rows
            int elem = (i * 256 + t) * 8;
            int row = elem >> 6, kk = elem & 63;
            int kks = kk ^ ((row & 7) << 3);          // inverse-swizzled source
            load_lds_16B(featb + (featrow + miL[row]) * 384 + k0 + kks, &As[elem]);
        }
        #pragma unroll
        for (int i = 0; i < 3; i++) {                 // B: 96x64 weight slice
            int elem = (i * 256 + t) * 8;
            int cn = elem >> 6, kk = elem & 63;
            int kks = kk ^ ((cn & 7) << 3);
            load_lds_16B(wqkvb + (size_t)(h * 96 + cn) * 384 + k0 + kks, &Bs[elem]);
        }
        __syncthreads();
        #pragma unroll
        for (int kk = 0; kk < 64; kk += 32) {
            bf16x8 af[4], bfr[3];
            #pragma unroll
            for (int m = 0; m < 4; m++) {
                int row = wr * 64 + m * 16 + fr;
                af[m] = *reinterpret_cast<const bf16x8*>(&As[row * 64 + ((kk + fq * 8) ^ ((row & 7) << 3))]);
            }
            #pragma unroll
            for (int n = 0; n < 3; n++) {
                int row = wc * 48 + n * 16 + fr;
                bfr[n] = *reinterpret_cast<const bf16x8*>(&Bs[row * 64 + ((kk + fq * 8) ^ ((row & 7) << 3))]);
            }
            #pragma unroll
            for (int m = 0; m < 4; m++)
                #pragma unroll
                for (int n = 0; n < 3; n++)
                    acc[m][n] = __builtin_amdgcn_mfma_f32_16x16x32_bf16(af[m], bfr[n], acc[m][n], 0, 0, 0);
        }
        __syncthreads();
    }
    // epilogue: col cn = h-local qkv col (s = cn>>4: 0=q, 1=k, 2..5=v)
    #pragma unroll
    for (int n = 0; n < 3; n++) {
        int cn = wc * 48 + n * 16 + fr;
        int s = cn >> 4, c = cn & 15;
        float bc = bias[h * 96 + cn];
        #pragma unroll
        for (int m = 0; m < 4; m++) {
            #pragma unroll
            for (int r = 0; r < 4; r++) {
                int mm = bm + wr * 64 + m * 16 + fq * 4 + r;     // kcm index
                float v = acc[m][n][r] + bc;
                __hip_bfloat16 hv = __float2bfloat16(v);
                ushort u = *(const ushort*)&hv;
                if (s == 0)      q_g[((size_t)bh * N_ + mm) * 16 + c] = u;
                else if (s == 1) k_g[((size_t)bh * N_ + mm) * 16 + c] = u;
                else             vt_g[((size_t)bh * 2048 + (mm >> 8) * 64 + (cn - 32)) * 256 + (mm & 255)] = u;
            }
        }
    }
}

// ---------------------------------------------------------------- MFMA attention
// One block per (b,kc,h), 512 threads = 8 waves; wave w owns query rows 32w..32w+31.
// ALL staging is contiguous (gather was done by gemm_qkv_g).
// Swapped QK^T: S'[j][i] = K·Q^T so each lane holds a full j-row for one query i.
// C/D layout (32x32): col = lane&31, row = (r&3) + 8*(r>>2) + 4*(lane>>5).
__global__ __launch_bounds__(512, 2) void attn_kernel(const ushort* __restrict__ q_g,
                                                      const ushort* __restrict__ k_g,
                                                      const ushort* __restrict__ vt_g,
                                                      const int* __restrict__ member_idx,
                                                      const float* __restrict__ pos,
                                                      const float* __restrict__ w_pos,
                                                      const unsigned* __restrict__ pmax_u,
                                                      ushort* __restrict__ feat2) {
    const int h = blockIdx.x, kc = blockIdx.y, b = blockIdx.z;
    const int bh = b * H_ + h;
    __shared__ ushort Ks[M_ * 16];        // 8 KB  [member][16]
    __shared__ ushort Vt[64 * VSTR];      // 32.5 KB [channel][member], padded stride
    __shared__ float  SpA[M_];            // bias*log2e, crow-reordered
    __shared__ int    Idx[M_];
    __shared__ float  dinvS[8 * 32];

    const int t  = threadIdx.x;
    const int w  = t >> 6, l = t & 63;
    const int hi = l >> 5, ln = l & 31;
    const size_t cbase = (size_t)bh * N_ + kc * M_;     // kcm base for this cluster
    const size_t rowbase = (size_t)b * N_;
    const float scale2 = 0.17677669529663687f * LOG2E;  // (C/H)^-0.5 * log2(e)

    // ---- bias + Idx (only gather left: pos rows; tiny, overlapped)
    if (t < M_) {
        int n = member_idx[cbase + t];
        Idx[t] = n;
        float inv0 = 1.f / __uint_as_float(pmax_u[0]);
        float inv1 = 1.f / __uint_as_float(pmax_u[1]);
        float sp = pos[(rowbase + n) * 2 + 0] * inv0 * w_pos[h * 2 + 0]
                 + pos[(rowbase + n) * 2 + 1] * inv1 * w_pos[h * 2 + 1];
        int jj = t & 31, jt = t >> 5;
        int r  = (jj & 3) | ((jj >> 3) << 2);
        int hb = (jj >> 2) & 1;
        SpA[jt * 32 + hb * 16 + r] = sp * LOG2E;
    }
    // ---- K: one linear global_load_lds per thread (8 KB contiguous)
    load_lds_16B(k_g + cbase * 16 + t * 8, &Ks[t * 8]);
    // ---- Vt: coalesced b128 copies into padded rows (no packing)
    {
        const ushort* vsrc = vt_g + ((size_t)bh * 2048 + kc * 64) * 256;
        #pragma unroll
        for (int it = 0; it < 4; it++) {
            int e = (it * 512 + t) * 8;
            int vc = e >> 8, m = e & 255;
            ushort8v vv = *reinterpret_cast<const ushort8v*>(vsrc + e);
            *reinterpret_cast<ushort8v*>(&Vt[vc * VSTR + m]) = vv;
        }
    }
    __syncthreads();

    // ---- Q B-frag direct from global (contiguous rows)
    const int iq = 32 * w + ln;
    bf16x8 qf = *reinterpret_cast<const bf16x8*>(q_g + (cbase + iq) * 16 + hi * 8);

    // ---- QK^T: 8 j-tiles of 32x32
    f32x16 zero16;
    #pragma unroll
    for (int i = 0; i < 16; i++) zero16[i] = 0.f;
    f32x16 sac[8];
    #pragma unroll
    for (int jt = 0; jt < 8; jt++) {
        bf16x8 kf = *reinterpret_cast<const bf16x8*>(&Ks[(32 * jt + ln) * 16 + hi * 8]);
        sac[jt] = __builtin_amdgcn_mfma_f32_32x32x16_bf16(kf, qf, zero16, 0, 0, 0);
    }

    // ---- softmax in log2 domain (lane-local + one cross-half exchange)
    float mx = -3.0e38f;
    #pragma unroll
    for (int jt = 0; jt < 8; jt++) {
        f32x4 bia[4];
        #pragma unroll
        for (int q4 = 0; q4 < 4; q4++)
            bia[q4] = *reinterpret_cast<const f32x4*>(&SpA[jt * 32 + hi * 16 + q4 * 4]);
        #pragma unroll
        for (int r = 0; r < 16; r++)
            sac[jt][r] = fmaf(sac[jt][r], scale2, bia[r >> 2][r & 3]);
        #pragma unroll
        for (int r = 0; r < 16; r += 2)
            mx = fmaxf(mx, fmaxf(sac[jt][r], sac[jt][r + 1]));   // -> v_max3
    }
    mx = fmaxf(mx, __shfl_xor(mx, 32));
    float sum = 0.f;
    #pragma unroll
    for (int jt = 0; jt < 8; jt++)
        #pragma unroll
        for (int r = 0; r < 16; r++) {
            float p = exp2f(sac[jt][r] - mx);
            sac[jt][r] = p;
            sum += p;
        }
    sum += __shfl_xor(sum, 32);
    float inv = 1.f / sum;
    if (hi == 0) dinvS[w * 32 + ln] = inv;

    // ---- PV: O[i][c] = sum_j P[j][i] V[j][c]; A-frag via cvt_pk+permlane
    f32x16 oa0 = zero16, oa1 = zero16;
    #pragma unroll
    for (int g = 0; g < 16; g++) {
        const int jt = g >> 1, hf = (g & 1) * 8;
        unsigned a0 = cvtpk_bf16(sac[jt][hf + 0], sac[jt][hf + 1]);
        unsigned a1 = cvtpk_bf16(sac[jt][hf + 2], sac[jt][hf + 3]);
        unsigned b0 = cvtpk_bf16(sac[jt][hf + 4], sac[jt][hf + 5]);
        unsigned b1 = cvtpk_bf16(sac[jt][hf + 6], sac[jt][hf + 7]);
        asm("v_permlane32_swap_b32 %0, %1" : "+v"(a0), "+v"(b0));
        asm("v_permlane32_swap_b32 %0, %1" : "+v"(a1), "+v"(b1));
        union { unsigned u[4]; bf16x8 v; } pa;
        pa.u[0] = a0; pa.u[1] = a1; pa.u[2] = b0; pa.u[3] = b1;
        union { ushort4v hv[2]; bf16x8 v; } vf0, vf1;
        vf0.hv[0] = *reinterpret_cast<const ushort4v*>(&Vt[ln * VSTR + g * 16 + hi * 8]);
        vf0.hv[1] = *reinterpret_cast<const ushort4v*>(&Vt[ln * VSTR + g * 16 + hi * 8 + 4]);
        vf1.hv[0] = *reinterpret_cast<const ushort4v*>(&Vt[(ln + 32) * VSTR + g * 16 + hi * 8]);
        vf1.hv[1] = *reinterpret_cast<const ushort4v*>(&Vt[(ln + 32) * VSTR + g * 16 + hi * 8 + 4]);
        oa0 = __builtin_amdgcn_mfma_f32_32x32x16_bf16(pa.v, vf0.v, oa0, 0, 0, 0);
        oa1 = __builtin_amdgcn_mfma_f32_32x32x16_bf16(pa.v, vf1.v, oa1, 0, 0, 0);
    }

    // ---- epilogue: lane holds O[i=crow(r,hi)][c=ln(+32)]; scatter bf16 rows
    #pragma unroll
    for (int r = 0; r < 16; r++) {
        int crow = (r & 3) + 8 * (r >> 2) + 4 * hi;
        float dv = dinvS[w * 32 + crow];
        int ni = Idx[32 * w + crow];
        __hip_bfloat16 o0 = __float2bfloat16(oa0[r] * dv);
        __hip_bfloat16 o1 = __float2bfloat16(oa1[r] * dv);
        ushort* dst = feat2 + (rowbase + ni) * F2D + h * 64 + ln;
        dst[0]  = *(const ushort*)&o0;
        dst[32] = *(const ushort*)&o1;
    }
}

// ---------------------------------------------------------------- proj GEMM (128x128, BK=64)
// XCD-aware 1-D remap + T2 LDS swizzle.
template<int Kdim, int Ndim, bool OUT_BF16>
__global__ __launch_bounds__(256) void gemm_mfma(const ushort* __restrict__ A,
                                                 const ushort* __restrict__ Bw,
                                                 const float* __restrict__ bias,
                                                 void* __restrict__ Cout) {
    constexpr int NB = Ndim / 128;
    __shared__ ushort As[128 * 64];
    __shared__ ushort Bs[128 * 64];
    const int wgid = blockIdx.x;
    const int xcd  = wgid & 7;
    const int loc  = wgid >> 3;
    const int bm = (xcd * 32 + loc / NB) * 128;
    const int bn = (loc % NB) * 128;
    const int t = threadIdx.x;
    const int l = t & 63;
    const int wr = (t >> 6) >> 1, wc = (t >> 6) & 1;
    const int fr = l & 15, fq = l >> 4;

    f32x4 zero = {0.f, 0.f, 0.f, 0.f};
    f32x4 acc[4][4];
    #pragma unroll
    for (int m = 0; m < 4; m++)
        #pragma unroll
        for (int n = 0; n < 4; n++) acc[m][n] = zero;

    for (int k0 = 0; k0 < Kdim; k0 += 64) {
        #pragma unroll
        for (int i = 0; i < 4; i++) {
            int elem = (i * 256 + t) * 8;
            int row = elem >> 6, kk = elem & 63;
            int kks = kk ^ ((row & 7) << 3);
            load_lds_16B(A + (size_t)(bm + row) * Kdim + k0 + kks, &As[elem]);
        }
        #pragma unroll
        for (int i = 0; i < 4; i++) {
            int elem = (i * 256 + t) * 8;
            int row = elem >> 6, kk = elem & 63;
            int kks = kk ^ ((row & 7) << 3);
            load_lds_16B(Bw + (size_t)(bn + row) * Kdim + k0 + kks, &Bs[elem]);
        }
        __syncthreads();
        #pragma unroll
        for (int kk = 0; kk < 64; kk += 32) {
            bf16x8 af[4], bfr[4];
            #pragma unroll
            for (int m = 0; m < 4; m++) {
                int row = wr * 64 + m * 16 + fr;
                af[m] = *reinterpret_cast<const bf16x8*>(&As[row * 64 + ((kk + fq * 8) ^ ((row & 7) << 3))]);
            }
            #pragma unroll
            for (int n = 0; n < 4; n++) {
                int row = wc * 64 + n * 16 + fr;
                bfr[n] = *reinterpret_cast<const bf16x8*>(&Bs[row * 64 + ((kk + fq * 8) ^ ((row & 7) << 3))]);
            }
            #pragma unroll
            for (int m = 0; m < 4; m++)
                #pragma unroll
                for (int n = 0; n < 4; n++)
                    acc[m][n] = __builtin_amdgcn_mfma_f32_16x16x32_bf16(af[m], bfr[n], acc[m][n], 0, 0, 0);
        }
        __syncthreads();
    }
    #pragma unroll
    for (int n = 0; n < 4; n++) {
        int col = bn + wc * 64 + n * 16 + fr;
        float bc = bias[col];
        #pragma unroll
        for (int m = 0; m < 4; m++) {
            #pragma unroll
            for (int r = 0; r < 4; r++) {
                size_t row = bm + wr * 64 + m * 16 + fq * 4 + r;
                float v = acc[m][n][r] + bc;
                if (OUT_BF16) {
                    __hip_bfloat16 hv = __float2bfloat16(v);
                    ((ushort*)Cout)[row * Ndim + col] = *(const ushort*)&hv;
                } else {
                    ((float*)Cout)[row * Ndim + col] = v;
                }
            }
        }
    }
}

// ---------------------------------------------------------------- launch
extern "C" void kernel_launch(void* const* d_in, const int* in_sizes, int n_in,
                              void* d_out, int out_size, void* d_ws, size_t ws_size,
                              hipStream_t stream) {
    const float* pos    = (const float*)d_in[0];
    const float* feat   = (const float*)d_in[1];
    const int*   midx   = (const int*)  d_in[2];
    const float* w_qkv  = (const float*)d_in[3];
    const float* b_qkv  = (const float*)d_in[4];
    const float* w_pos  = (const float*)d_in[5];
    const float* b_pos  = (const float*)d_in[6];  (void)b_pos; // cancels in softmax
    const float* w_proj = (const float*)d_in[7];
    const float* b_proj = (const float*)d_in[8];
    float* out = (float*)d_out;

    // workspace (126.4 MB peak, same as prior rounds):
    // [pmax 256B | wproj 0.59MB | q_g 12.6 | k_g 12.6 | vt_g 50.3 |
    //  REGION: {featb 25.2 + wqkvb 0.88} reused as feat2 50.3]
    char* ws = (char*)d_ws;
    unsigned* pmax  = (unsigned*)ws;
    ushort*   wproj = (ushort*)(ws + 256);
    ushort*   q_g   = (ushort*)(ws + 256 + 589824);
    ushort*   k_g   = (ushort*)(ws + 256 + 589824 + 12582912);
    ushort*   vt_g  = (ushort*)(ws + 256 + 589824 + 2 * 12582912);
    char*     region = ws + 256 + 589824 + 2 * 12582912 + 50331648;
    ushort*   featb = (ushort*)region;
    ushort*   wqkvb = (ushort*)(region + 25165824);
    ushort*   feat2 = (ushort*)region;   // overwrites featb/wqkvb after gemm_qkv_g

    hipMemsetAsync(pmax, 0, 8, stream);  // ws is NOT re-poisoned between replays
    posmax_kernel<<<64, 256, 0, stream>>>(pos, pmax);
    cast_kernel<<<(BN_ * C_ / 4 + 255) / 256, 256, 0, stream>>>(feat, featb, BN_ * C_ / 4);
    cast_kernel<<<(3 * C_ * C_ / 4 + 255) / 256, 256, 0, stream>>>(w_qkv, wqkvb, 3 * C_ * C_ / 4);
    cast_kernel<<<(C_ * F2D / 4 + 255) / 256, 256, 0, stream>>>(w_proj, wproj, C_ * F2D / 4);
    gemm_qkv_g<<<dim3(64, 48), 256, 0, stream>>>(featb, wqkvb, b_qkv, midx, q_g, k_g, vt_g);
    attn_kernel<<<dim3(H_, K_, B_), 512, 0, stream>>>(q_g, k_g, vt_g, midx, pos, w_pos, pmax, feat2);
    gemm_mfma<768, C_, false><<<8 * 32 * (C_ / 128), 256, 0, stream>>>(feat2, wproj, b_proj, out);
}

// Round 8
// 172.403 us; speedup vs baseline: 1.1700x; 1.1700x over previous
//
#include <hip/hip_runtime.h>
#include <hip/hip_bf16.h>

// Problem constants (B,N,C,H,D,K) = (4, 8192, 384, 12, 2, 32)
#define B_  4
#define N_  8192
#define C_  384
#define H_  12
#define K_  32
#define M_  256          // N/K members per cluster
#define BN_ (B_*N_)      // 32768 rows
#define QKVD 1152        // 3*C  (per-head layout: h*96 + s*16 + c, s in 0..5)
#define F2D 768          // 2*C
#define VSTR 260         // Vt row stride in elems (520B): 2-way on b64 reads (free)
#define LOG2E 1.4426950408889634f

typedef __attribute__((ext_vector_type(8)))  short  bf16x8;
typedef __attribute__((ext_vector_type(4)))  float  f32x4;
typedef __attribute__((ext_vector_type(16))) float  f32x16;
typedef __attribute__((ext_vector_type(4)))  ushort ushort4v;
typedef __attribute__((ext_vector_type(8)))  ushort ushort8v;

#define GLOBAL_AS __attribute__((address_space(1)))
#define LDS_AS    __attribute__((address_space(3)))

__device__ __forceinline__ void load_lds_16B(const ushort* g, ushort* l) {
    __builtin_amdgcn_global_load_lds((const GLOBAL_AS unsigned int*)g,
                                     (LDS_AS unsigned int*)l, 16, 0, 0);
}
__device__ __forceinline__ unsigned cvtpk_bf16(float lo, float hi) {
    unsigned r;
    asm("v_cvt_pk_bf16_f32 %0, %1, %2" : "=v"(r) : "v"(lo), "v"(hi));
    return r;
}

// ---------------------------------------------------------------- pos max
__global__ void posmax_kernel(const float* __restrict__ pos, unsigned* __restrict__ pmax) {
    int tid = blockIdx.x * blockDim.x + threadIdx.x;
    float m0 = 0.f, m1 = 0.f;
    for (int i = tid; i < BN_; i += gridDim.x * blockDim.x) {
        m0 = fmaxf(m0, pos[(size_t)i * 2 + 0]);
        m1 = fmaxf(m1, pos[(size_t)i * 2 + 1]);
    }
    #pragma unroll
    for (int off = 32; off; off >>= 1) {
        m0 = fmaxf(m0, __shfl_down(m0, off));
        m1 = fmaxf(m1, __shfl_down(m1, off));
    }
    __shared__ float s0[4], s1[4];
    int w = threadIdx.x >> 6;
    if ((threadIdx.x & 63) == 0) { s0[w] = m0; s1[w] = m1; }
    __syncthreads();
    if (threadIdx.x == 0) {
        for (int i = 1; i < 4; i++) { m0 = fmaxf(m0, s0[i]); m1 = fmaxf(m1, s1[i]); }
        atomicMax(&pmax[0], __float_as_uint(m0));   // pos >= 0: float order == uint order
        atomicMax(&pmax[1], __float_as_uint(m1));
    }
}

// ---------------------------------------------------------------- weights f32 -> bf16 (fused)
#define WQN 110592   // 3*C*C/4 granules
#define WPN 73728    // C*F2D/4 granules
__global__ __launch_bounds__(256) void cast_w(const float* __restrict__ wq,
                                              const float* __restrict__ wp,
                                              ushort* __restrict__ wqb,
                                              ushort* __restrict__ wpb) {
    int i = blockIdx.x * 256 + threadIdx.x;
    const float* src; ushort* dst; int j;
    if (i < WQN) { src = wq; dst = wqb; j = i; }
    else         { src = wp; dst = wpb; j = i - WQN; }
    float4 a = reinterpret_cast<const float4*>(src)[j];
    ushort2 lo = { (ushort)(cvtpk_bf16(a.x, a.y) & 0xffff), (ushort)(cvtpk_bf16(a.x, a.y) >> 16) };
    (void)lo;
    unsigned u01 = cvtpk_bf16(a.x, a.y), u23 = cvtpk_bf16(a.z, a.w);
    ushort4 o = { (ushort)(u01 & 0xffff), (ushort)(u01 >> 16), (ushort)(u23 & 0xffff), (ushort)(u23 >> 16) };
    reinterpret_cast<ushort4*>(dst)[j] = o;
}

// ---------------------------------------------------------------- QKV GEMM (f32 A in-kernel cast)
// 128x128 tile, BK=64, XCD-aware 1-D grid. A: feat f32 reg-staged + cvt_pk + swizzled
// ds_write (no featb round-trip). B: bf16 weights via global_load_lds, pre-swizzled source.
__global__ __launch_bounds__(256) void gemm_qkv_f(const float* __restrict__ feat,
                                                  const ushort* __restrict__ wqkvb,
                                                  const float* __restrict__ bias,
                                                  ushort* __restrict__ qkv) {
    constexpr int NB = QKVD / 128;            // 9 column blocks
    __shared__ ushort As[128 * 64];
    __shared__ ushort Bs[128 * 64];
    const int wgid = blockIdx.x;
    const int xcd  = wgid & 7;
    const int loc  = wgid >> 3;
    const int bm = (xcd * 32 + loc / NB) * 128;
    const int bn = (loc % NB) * 128;
    const int t = threadIdx.x;
    const int l = t & 63;
    const int wr = (t >> 6) >> 1, wc = (t >> 6) & 1;
    const int fr = l & 15, fq = l >> 4;

    f32x4 zero = {0.f, 0.f, 0.f, 0.f};
    f32x4 acc[4][4];
    #pragma unroll
    for (int m = 0; m < 4; m++)
        #pragma unroll
        for (int n = 0; n < 4; n++) acc[m][n] = zero;

    for (int k0 = 0; k0 < 384; k0 += 64) {
        // A: 128x64 f32 -> bf16, swizzled ds_write_b128 (8-elem granules)
        #pragma unroll
        for (int i = 0; i < 4; i++) {
            int g = i * 256 + t;
            int row = g >> 3, c8 = (g & 7) * 8;
            const float* src = feat + (size_t)(bm + row) * 384 + k0 + c8;
            float4 a = *reinterpret_cast<const float4*>(src);
            float4 bq = *reinterpret_cast<const float4*>(src + 4);
            union { unsigned u[4]; ushort8v v; } pk;
            pk.u[0] = cvtpk_bf16(a.x, a.y);  pk.u[1] = cvtpk_bf16(a.z, a.w);
            pk.u[2] = cvtpk_bf16(bq.x, bq.y); pk.u[3] = cvtpk_bf16(bq.z, bq.w);
            *reinterpret_cast<ushort8v*>(&As[row * 64 + (c8 ^ ((row & 7) << 3))]) = pk.v;
        }
        // B: bf16 weights via gll, pre-swizzled source
        #pragma unroll
        for (int i = 0; i < 4; i++) {
            int elem = (i * 256 + t) * 8;
            int row = elem >> 6, kk = elem & 63;
            int kks = kk ^ ((row & 7) << 3);
            load_lds_16B(wqkvb + (size_t)(bn + row) * 384 + k0 + kks, &Bs[elem]);
        }
        __syncthreads();
        #pragma unroll
        for (int kk = 0; kk < 64; kk += 32) {
            bf16x8 af[4], bfr[4];
            #pragma unroll
            for (int m = 0; m < 4; m++) {
                int row = wr * 64 + m * 16 + fr;
                af[m] = *reinterpret_cast<const bf16x8*>(&As[row * 64 + ((kk + fq * 8) ^ ((row & 7) << 3))]);
            }
            #pragma unroll
            for (int n = 0; n < 4; n++) {
                int row = wc * 64 + n * 16 + fr;
                bfr[n] = *reinterpret_cast<const bf16x8*>(&Bs[row * 64 + ((kk + fq * 8) ^ ((row & 7) << 3))]);
            }
            #pragma unroll
            for (int m = 0; m < 4; m++)
                #pragma unroll
                for (int n = 0; n < 4; n++)
                    acc[m][n] = __builtin_amdgcn_mfma_f32_16x16x32_bf16(af[m], bfr[n], acc[m][n], 0, 0, 0);
        }
        __syncthreads();
    }
    #pragma unroll
    for (int n = 0; n < 4; n++) {
        int col = bn + wc * 64 + n * 16 + fr;
        float bc = bias[col];
        #pragma unroll
        for (int m = 0; m < 4; m++) {
            #pragma unroll
            for (int r = 0; r < 4; r++) {
                size_t row = bm + wr * 64 + m * 16 + fq * 4 + r;
                __hip_bfloat16 hv = __float2bfloat16(acc[m][n][r] + bc);
                qkv[row * QKVD + col] = *(const ushort*)&hv;
            }
        }
    }
}

// ---------------------------------------------------------------- MFMA attention
// One block per (b,kc,h), 512 threads = 8 waves; wave w owns query rows 32w..32w+31.
// Gather-BW-bound: Q/V issued to regs before barrier (latency under bias calc);
// V pack-transpose deferred to after softmax. Swapped QK^T: S'[j][i] = K·Q^T.
// C/D layout (32x32): col = lane&31, row = (r&3) + 8*(r>>2) + 4*(lane>>5).
__global__ __launch_bounds__(512, 2) void attn_kernel(const ushort* __restrict__ qkv,
                                                      const int* __restrict__ member_idx,
                                                      const float* __restrict__ pos,
                                                      const float* __restrict__ w_pos,
                                                      const unsigned* __restrict__ pmax_u,
                                                      ushort* __restrict__ feat2) {
    const int h = blockIdx.x, kc = blockIdx.y, b = blockIdx.z;
    __shared__ ushort Ks[M_ * 16];        // 8 KB  [member][16]
    __shared__ ushort Vt[64 * VSTR];      // 32.5 KB [channel][member], padded stride
    __shared__ float  SpA[M_];            // bias*log2e, crow-reordered
    __shared__ int    Idx[M_];
    __shared__ float  dinvS[8 * 32];

    const int t  = threadIdx.x;
    const int w  = t >> 6, l = t & 63;
    const int hi = l >> 5, ln = l & 31;
    const int* mi = member_idx + (((size_t)b * H_ + h) * K_ + kc) * M_;
    const size_t rowbase = (size_t)b * N_;
    const float scale2 = 0.17677669529663687f * LOG2E;  // (C/H)^-0.5 * log2(e)

    // ---- early issue: Q fragment (regs)
    const int iq = 32 * w + ln;
    const int nq = mi[iq];
    bf16x8 qf = *(const bf16x8*)(qkv + (rowbase + nq) * QKVD + h * 96 + hi * 8);
    // ---- early issue: V rows to regs (pack deferred past softmax)
    const int u = t >> 2, cq = t & 3;
    const int n0 = mi[2 * u], n1 = mi[2 * u + 1];
    const ushort* s0 = qkv + (rowbase + n0) * QKVD + h * 96 + 32 + cq * 16;
    const ushort* s1 = qkv + (rowbase + n1) * QKVD + h * 96 + 32 + cq * 16;
    ushort8v v0a = *(const ushort8v*)s0;
    ushort8v v0b = *(const ushort8v*)(s0 + 8);
    ushort8v v1a = *(const ushort8v*)s1;
    ushort8v v1b = *(const ushort8v*)(s1 + 8);
    // ---- K stage via global_load_lds (per-lane gather source, linear LDS dest)
    {
        int row = t >> 1, half = t & 1;
        int n = mi[row];
        load_lds_16B(qkv + (rowbase + n) * QKVD + h * 96 + 16 + half * 8, &Ks[t * 8]);
    }
    // ---- bias + Idx (crow-reordered); overlaps the in-flight loads above
    if (t < M_) {
        int n = mi[t];
        Idx[t] = n;
        float inv0 = 1.f / __uint_as_float(pmax_u[0]);
        float inv1 = 1.f / __uint_as_float(pmax_u[1]);
        float sp = pos[(rowbase + n) * 2 + 0] * inv0 * w_pos[h * 2 + 0]
                 + pos[(rowbase + n) * 2 + 1] * inv1 * w_pos[h * 2 + 1];
        int jj = t & 31, jt = t >> 5;
        int r  = (jj & 3) | ((jj >> 3) << 2);
        int hb = (jj >> 2) & 1;
        SpA[jt * 32 + hb * 16 + r] = sp * LOG2E;
    }
    __syncthreads();

    // ---- QK^T: 8 j-tiles of 32x32
    f32x16 zero16;
    #pragma unroll
    for (int i = 0; i < 16; i++) zero16[i] = 0.f;
    f32x16 sac[8];
    __builtin_amdgcn_s_setprio(1);
    #pragma unroll
    for (int jt = 0; jt < 8; jt++) {
        bf16x8 kf = *(const bf16x8*)&Ks[(32 * jt + ln) * 16 + hi * 8];
        sac[jt] = __builtin_amdgcn_mfma_f32_32x32x16_bf16(kf, qf, zero16, 0, 0, 0);
    }
    __builtin_amdgcn_s_setprio(0);

    // ---- softmax in log2 domain (lane-local + one cross-half exchange)
    float mx = -3.0e38f;
    #pragma unroll
    for (int jt = 0; jt < 8; jt++) {
        f32x4 bia[4];
        #pragma unroll
        for (int q4 = 0; q4 < 4; q4++)
            bia[q4] = *(const f32x4*)&SpA[jt * 32 + hi * 16 + q4 * 4];
        #pragma unroll
        for (int r = 0; r < 16; r++)
            sac[jt][r] = fmaf(sac[jt][r], scale2, bia[r >> 2][r & 3]);
        #pragma unroll
        for (int r = 0; r < 16; r += 2)
            mx = fmaxf(mx, fmaxf(sac[jt][r], sac[jt][r + 1]));   // -> v_max3
    }
    mx = fmaxf(mx, __shfl_xor(mx, 32));
    float sum = 0.f;
    #pragma unroll
    for (int jt = 0; jt < 8; jt++)
        #pragma unroll
        for (int r = 0; r < 16; r++) {
            float p = exp2f(sac[jt][r] - mx);
            sac[jt][r] = p;
            sum += p;
        }
    sum += __shfl_xor(sum, 32);
    float inv = 1.f / sum;
    if (hi == 0) dinvS[w * 32 + ln] = inv;

    // ---- deferred V pack-transpose (regs long since landed)
    #pragma unroll
    for (int i = 0; i < 8; i++) {
        int c0 = cq * 16 + i, c1 = cq * 16 + 8 + i;
        *(unsigned*)&Vt[c0 * VSTR + 2 * u] = (unsigned)(ushort)v0a[i] | ((unsigned)(ushort)v1a[i] << 16);
        *(unsigned*)&Vt[c1 * VSTR + 2 * u] = (unsigned)(ushort)v0b[i] | ((unsigned)(ushort)v1b[i] << 16);
    }
    __syncthreads();

    // ---- PV: O[i][c] = sum_j P[j][i] V[j][c]; A-frag via cvt_pk+permlane
    f32x16 oa0 = zero16, oa1 = zero16;
    __builtin_amdgcn_s_setprio(1);
    #pragma unroll
    for (int g = 0; g < 16; g++) {
        const int jt = g >> 1, hf = (g & 1) * 8;
        unsigned a0 = cvtpk_bf16(sac[jt][hf + 0], sac[jt][hf + 1]);
        unsigned a1 = cvtpk_bf16(sac[jt][hf + 2], sac[jt][hf + 3]);
        unsigned b0 = cvtpk_bf16(sac[jt][hf + 4], sac[jt][hf + 5]);
        unsigned b1 = cvtpk_bf16(sac[jt][hf + 6], sac[jt][hf + 7]);
        asm("v_permlane32_swap_b32 %0, %1" : "+v"(a0), "+v"(b0));
        asm("v_permlane32_swap_b32 %0, %1" : "+v"(a1), "+v"(b1));
        union { unsigned uu[4]; bf16x8 v; } pa;
        pa.uu[0] = a0; pa.uu[1] = a1; pa.uu[2] = b0; pa.uu[3] = b1;
        union { ushort4v hv[2]; bf16x8 v; } vf0, vf1;
        vf0.hv[0] = *(const ushort4v*)&Vt[ln * VSTR + g * 16 + hi * 8];
        vf0.hv[1] = *(const ushort4v*)&Vt[ln * VSTR + g * 16 + hi * 8 + 4];
        vf1.hv[0] = *(const ushort4v*)&Vt[(ln + 32) * VSTR + g * 16 + hi * 8];
        vf1.hv[1] = *(const ushort4v*)&Vt[(ln + 32) * VSTR + g * 16 + hi * 8 + 4];
        oa0 = __builtin_amdgcn_mfma_f32_32x32x16_bf16(pa.v, vf0.v, oa0, 0, 0, 0);
        oa1 = __builtin_amdgcn_mfma_f32_32x32x16_bf16(pa.v, vf1.v, oa1, 0, 0, 0);
    }
    __builtin_amdgcn_s_setprio(0);

    // ---- epilogue: lane holds O[i=crow(r,hi)][c=ln(+32)]; scatter bf16 rows
    #pragma unroll
    for (int r = 0; r < 16; r++) {
        int crow = (r & 3) + 8 * (r >> 2) + 4 * hi;
        float dv = dinvS[w * 32 + crow];
        int ni = Idx[32 * w + crow];
        __hip_bfloat16 o0 = __float2bfloat16(oa0[r] * dv);
        __hip_bfloat16 o1 = __float2bfloat16(oa1[r] * dv);
        ushort* dst = feat2 + (rowbase + ni) * F2D + h * 64 + ln;
        dst[0]  = *(const ushort*)&o0;
        dst[32] = *(const ushort*)&o1;
    }
}

// ---------------------------------------------------------------- proj GEMM (128x128, BK=64)
// XCD-aware 1-D remap + T2 LDS swizzle.
template<int Kdim, int Ndim, bool OUT_BF16>
__global__ __launch_bounds__(256) void gemm_mfma(const ushort* __restrict__ A,
                                                 const ushort* __restrict__ Bw,
                                                 const float* __restrict__ bias,
                                                 void* __restrict__ Cout) {
    constexpr int NB = Ndim / 128;
    __shared__ ushort As[128 * 64];
    __shared__ ushort Bs[128 * 64];
    const int wgid = blockIdx.x;
    const int xcd  = wgid & 7;
    const int loc  = wgid >> 3;
    const int bm = (xcd * 32 + loc / NB) * 128;
    const int bn = (loc % NB) * 128;
    const int t = threadIdx.x;
    const int l = t & 63;
    const int wr = (t >> 6) >> 1, wc = (t >> 6) & 1;
    const int fr = l & 15, fq = l >> 4;

    f32x4 zero = {0.f, 0.f, 0.f, 0.f};
    f32x4 acc[4][4];
    #pragma unroll
    for (int m = 0; m < 4; m++)
        #pragma unroll
        for (int n = 0; n < 4; n++) acc[m][n] = zero;

    for (int k0 = 0; k0 < Kdim; k0 += 64) {
        #pragma unroll
        for (int i = 0; i < 4; i++) {
            int elem = (i * 256 + t) * 8;
            int row = elem >> 6, kk = elem & 63;
            int kks = kk ^ ((row & 7) << 3);
            load_lds_16B(A + (size_t)(bm + row) * Kdim + k0 + kks, &As[elem]);
        }
        #pragma unroll
        for (int i = 0; i < 4; i++) {
            int elem = (i * 256 + t) * 8;
            int row = elem >> 6, kk = elem & 63;
            int kks = kk ^ ((row & 7) << 3);
            load_lds_16B(Bw + (size_t)(bn + row) * Kdim + k0 + kks, &Bs[elem]);
        }
        __syncthreads();
        #pragma unroll
        for (int kk = 0; kk < 64; kk += 32) {
            bf16x8 af[4], bfr[4];
            #pragma unroll
            for (int m = 0; m < 4; m++) {
                int row = wr * 64 + m * 16 + fr;
                af[m] = *reinterpret_cast<const bf16x8*>(&As[row * 64 + ((kk + fq * 8) ^ ((row & 7) << 3))]);
            }
            #pragma unroll
            for (int n = 0; n < 4; n++) {
                int row = wc * 64 + n * 16 + fr;
                bfr[n] = *reinterpret_cast<const bf16x8*>(&Bs[row * 64 + ((kk + fq * 8) ^ ((row & 7) << 3))]);
            }
            #pragma unroll
            for (int m = 0; m < 4; m++)
                #pragma unroll
                for (int n = 0; n < 4; n++)
                    acc[m][n] = __builtin_amdgcn_mfma_f32_16x16x32_bf16(af[m], bfr[n], acc[m][n], 0, 0, 0);
        }
        __syncthreads();
    }
    #pragma unroll
    for (int n = 0; n < 4; n++) {
        int col = bn + wc * 64 + n * 16 + fr;
        float bc = bias[col];
        #pragma unroll
        for (int m = 0; m < 4; m++) {
            #pragma unroll
            for (int r = 0; r < 4; r++) {
                size_t row = bm + wr * 64 + m * 16 + fq * 4 + r;
                float v = acc[m][n][r] + bc;
                if (OUT_BF16) {
                    __hip_bfloat16 hv = __float2bfloat16(v);
                    ((ushort*)Cout)[row * Ndim + col] = *(const ushort*)&hv;
                } else {
                    ((float*)Cout)[row * Ndim + col] = v;
                }
            }
        }
    }
}

// ---------------------------------------------------------------- launch
extern "C" void kernel_launch(void* const* d_in, const int* in_sizes, int n_in,
                              void* d_out, int out_size, void* d_ws, size_t ws_size,
                              hipStream_t stream) {
    const float* pos    = (const float*)d_in[0];
    const float* feat   = (const float*)d_in[1];
    const int*   midx   = (const int*)  d_in[2];
    const float* w_qkv  = (const float*)d_in[3];
    const float* b_qkv  = (const float*)d_in[4];
    const float* w_pos  = (const float*)d_in[5];
    const float* b_pos  = (const float*)d_in[6];  (void)b_pos; // cancels in softmax
    const float* w_proj = (const float*)d_in[7];
    const float* b_proj = (const float*)d_in[8];
    float* out = (float*)d_out;

    // workspace (126.4 MB peak, proven size):
    // [pmax 256B | qkv 75.5MB | wproj 0.59MB | feat2 50.3MB]
    // wqkvb (0.88MB) overlays feat2's head: written by cast_w, consumed by gemm_qkv_f,
    // dead before attn writes feat2.
    char* ws = (char*)d_ws;
    unsigned* pmax  = (unsigned*)ws;
    ushort*   qkv   = (ushort*)(ws + 256);
    ushort*   wproj = (ushort*)(ws + 256 + 75497472);
    ushort*   feat2 = (ushort*)(ws + 256 + 75497472 + 589824);
    ushort*   wqkvb = feat2;   // overlay (dead before attn)

    hipMemsetAsync(pmax, 0, 8, stream);  // ws is NOT re-poisoned between replays
    posmax_kernel<<<64, 256, 0, stream>>>(pos, pmax);
    cast_w<<<(WQN + WPN) / 256, 256, 0, stream>>>(w_qkv, w_proj, wqkvb, wproj);
    gemm_qkv_f<<<8 * 32 * (QKVD / 128), 256, 0, stream>>>(feat, wqkvb, b_qkv, qkv);
    attn_kernel<<<dim3(H_, K_, B_), 512, 0, stream>>>(qkv, midx, pos, w_pos, pmax, feat2);
    gemm_mfma<768, C_, false><<<8 * 32 * (C_ / 128), 256, 0, stream>>>(feat2, wproj, b_proj, out);
}

// Round 9
// 167.980 us; speedup vs baseline: 1.2008x; 1.0263x over previous
//
#include <hip/hip_runtime.h>
#include <hip/hip_bf16.h>

// Problem constants (B,N,C,H,D,K) = (4, 8192, 384, 12, 2, 32)
#define B_  4
#define N_  8192
#define C_  384
#define H_  12
#define K_  32
#define M_  256          // N/K members per cluster
#define BN_ (B_*N_)      // 32768 rows
#define QKVD 1152        // 3*C
#define VSTR 260         // Vt row stride in elems (520B): 2-way on b64 reads (free)
#define LOG2E 1.4426950408889634f

// qkv slab layout: [bh][n][96] (q16|k16|v64 per head) -> per-(b,h) slab 1.5MB
// feat2 slab layout: [bh][n][64] -> per-(b,h) slab 1MB

typedef __attribute__((ext_vector_type(8)))  short  bf16x8;
typedef __attribute__((ext_vector_type(4)))  float  f32x4;
typedef __attribute__((ext_vector_type(16))) float  f32x16;
typedef __attribute__((ext_vector_type(4)))  ushort ushort4v;
typedef __attribute__((ext_vector_type(8)))  ushort ushort8v;

#define GLOBAL_AS __attribute__((address_space(1)))
#define LDS_AS    __attribute__((address_space(3)))

__device__ __forceinline__ void load_lds_16B(const ushort* g, ushort* l) {
    __builtin_amdgcn_global_load_lds((const GLOBAL_AS unsigned int*)g,
                                     (LDS_AS unsigned int*)l, 16, 0, 0);
}
__device__ __forceinline__ unsigned cvtpk_bf16(float lo, float hi) {
    unsigned r;
    asm("v_cvt_pk_bf16_f32 %0, %1, %2" : "=v"(r) : "v"(lo), "v"(hi));
    return r;
}

// ---------------------------------------------------------------- pos max
__global__ void posmax_kernel(const float* __restrict__ pos, unsigned* __restrict__ pmax) {
    int tid = blockIdx.x * blockDim.x + threadIdx.x;
    float m0 = 0.f, m1 = 0.f;
    for (int i = tid; i < BN_; i += gridDim.x * blockDim.x) {
        m0 = fmaxf(m0, pos[(size_t)i * 2 + 0]);
        m1 = fmaxf(m1, pos[(size_t)i * 2 + 1]);
    }
    #pragma unroll
    for (int off = 32; off; off >>= 1) {
        m0 = fmaxf(m0, __shfl_down(m0, off));
        m1 = fmaxf(m1, __shfl_down(m1, off));
    }
    __shared__ float s0[4], s1[4];
    int w = threadIdx.x >> 6;
    if ((threadIdx.x & 63) == 0) { s0[w] = m0; s1[w] = m1; }
    __syncthreads();
    if (threadIdx.x == 0) {
        for (int i = 1; i < 4; i++) { m0 = fmaxf(m0, s0[i]); m1 = fmaxf(m1, s1[i]); }
        atomicMax(&pmax[0], __float_as_uint(m0));   // pos >= 0: float order == uint order
        atomicMax(&pmax[1], __float_as_uint(m1));
    }
}

// ---------------------------------------------------------------- f32 -> bf16 cast
__global__ __launch_bounds__(256) void cast_kernel(const float* __restrict__ src,
                                                   ushort* __restrict__ dst, int n4) {
    int i = blockIdx.x * blockDim.x + threadIdx.x;
    if (i >= n4) return;
    float4 a = reinterpret_cast<const float4*>(src)[i];
    unsigned u01 = cvtpk_bf16(a.x, a.y), u23 = cvtpk_bf16(a.z, a.w);
    ushort4 o = { (ushort)(u01 & 0xffff), (ushort)(u01 >> 16),
                  (ushort)(u23 & 0xffff), (ushort)(u23 >> 16) };
    reinterpret_cast<ushort4*>(dst)[i] = o;
}

// ---------------------------------------------------------------- weights f32 -> bf16 (fused)
#define WQN 110592   // 3*C*C/4 granules
#define WPN 73728    // C*2C/4 granules
__global__ __launch_bounds__(256) void cast_w(const float* __restrict__ wq,
                                              const float* __restrict__ wp,
                                              ushort* __restrict__ wqb,
                                              ushort* __restrict__ wpb) {
    int i = blockIdx.x * 256 + threadIdx.x;
    const float* src; ushort* dst; int j;
    if (i < WQN) { src = wq; dst = wqb; j = i; }
    else         { src = wp; dst = wpb; j = i - WQN; }
    float4 a = reinterpret_cast<const float4*>(src)[j];
    unsigned u01 = cvtpk_bf16(a.x, a.y), u23 = cvtpk_bf16(a.z, a.w);
    ushort4 o = { (ushort)(u01 & 0xffff), (ushort)(u01 >> 16),
                  (ushort)(u23 & 0xffff), (ushort)(u23 >> 16) };
    reinterpret_cast<ushort4*>(dst)[j] = o;
}

// ---------------------------------------------------------------- QKV GEMM
// 128x128, BK=64. gll-staged A/B with T2 swizzle (pre-swizzled source), XCD row-strip
// remap. Epilogue writes head-sliced qkv slabs [bh][n][96].
__global__ __launch_bounds__(256) void gemm_qkv_s(const ushort* __restrict__ A,
                                                  const ushort* __restrict__ Bw,
                                                  const float* __restrict__ bias,
                                                  ushort* __restrict__ qkv) {
    constexpr int NB = QKVD / 128;            // 9 column blocks
    __shared__ ushort As[128 * 64];
    __shared__ ushort Bs[128 * 64];
    const int wgid = blockIdx.x;
    const int xcd  = wgid & 7;
    const int loc  = wgid >> 3;
    const int bm = (xcd * 32 + loc / NB) * 128;
    const int bn = (loc % NB) * 128;
    const int t = threadIdx.x;
    const int l = t & 63;
    const int wr = (t >> 6) >> 1, wc = (t >> 6) & 1;
    const int fr = l & 15, fq = l >> 4;

    f32x4 zero = {0.f, 0.f, 0.f, 0.f};
    f32x4 acc[4][4];
    #pragma unroll
    for (int m = 0; m < 4; m++)
        #pragma unroll
        for (int n = 0; n < 4; n++) acc[m][n] = zero;

    for (int k0 = 0; k0 < 384; k0 += 64) {
        #pragma unroll
        for (int i = 0; i < 4; i++) {
            int elem = (i * 256 + t) * 8;
            int row = elem >> 6, kk = elem & 63;
            int kks = kk ^ ((row & 7) << 3);
            load_lds_16B(A + (size_t)(bm + row) * 384 + k0 + kks, &As[elem]);
        }
        #pragma unroll
        for (int i = 0; i < 4; i++) {
            int elem = (i * 256 + t) * 8;
            int row = elem >> 6, kk = elem & 63;
            int kks = kk ^ ((row & 7) << 3);
            load_lds_16B(Bw + (size_t)(bn + row) * 384 + k0 + kks, &Bs[elem]);
        }
        __syncthreads();
        #pragma unroll
        for (int kk = 0; kk < 64; kk += 32) {
            bf16x8 af[4], bfr[4];
            #pragma unroll
            for (int m = 0; m < 4; m++) {
                int row = wr * 64 + m * 16 + fr;
                af[m] = *reinterpret_cast<const bf16x8*>(&As[row * 64 + ((kk + fq * 8) ^ ((row & 7) << 3))]);
            }
            #pragma unroll
            for (int n = 0; n < 4; n++) {
                int row = wc * 64 + n * 16 + fr;
                bfr[n] = *reinterpret_cast<const bf16x8*>(&Bs[row * 64 + ((kk + fq * 8) ^ ((row & 7) << 3))]);
            }
            #pragma unroll
            for (int m = 0; m < 4; m++)
                #pragma unroll
                for (int n = 0; n < 4; n++)
                    acc[m][n] = __builtin_amdgcn_mfma_f32_16x16x32_bf16(af[m], bfr[n], acc[m][n], 0, 0, 0);
        }
        __syncthreads();
    }
    // epilogue -> qkv slab [bh][n][96]; tile rows all in one batch b (8192 % 128 == 0)
    const int bq = bm >> 13;          // batch
    const int nbase = bm & (N_ - 1);  // row within batch
    #pragma unroll
    for (int n = 0; n < 4; n++) {
        int col = bn + wc * 64 + n * 16 + fr;
        int hc = col / 96, cn = col % 96;
        float bc = bias[col];
        ushort* base = qkv + ((size_t)(bq * H_ + hc) * N_ + nbase) * 96 + cn;
        #pragma unroll
        for (int m = 0; m < 4; m++) {
            #pragma unroll
            for (int r = 0; r < 4; r++) {
                int rowoff = wr * 64 + m * 16 + fq * 4 + r;
                __hip_bfloat16 hv = __float2bfloat16(acc[m][n][r] + bc);
                base[(size_t)rowoff * 96] = *(const ushort*)&hv;
            }
        }
    }
}

// ---------------------------------------------------------------- MFMA attention
// 1-D grid: id = (bh>>3)*256 + kc*8 + (bh&7) -> all 32 kc-blocks of one bh land on
// one XCD (HW round-robin id%8): 1.5MB qkv slab + 1MB feat2 slab stay L2-resident.
// 512 threads = 8 waves; wave w owns query rows 32w..32w+31. Swapped QK^T.
// C/D layout (32x32): col = lane&31, row = (r&3) + 8*(r>>2) + 4*(lane>>5).
__global__ __launch_bounds__(512, 2) void attn_kernel(const ushort* __restrict__ qkv,
                                                      const int* __restrict__ member_idx,
                                                      const float* __restrict__ pos,
                                                      const float* __restrict__ w_pos,
                                                      const unsigned* __restrict__ pmax_u,
                                                      ushort* __restrict__ feat2) {
    const int id = blockIdx.x;
    const int bh = (id >> 8) * 8 + (id & 7);
    const int kc = (id >> 3) & 31;
    const int b = bh / H_, h = bh % H_;
    __shared__ ushort Ks[M_ * 16];        // 8 KB  [member][16]
    __shared__ ushort Vt[64 * VSTR];      // 32.5 KB [channel][member], padded stride
    __shared__ float  SpA[M_];            // bias*log2e, crow-reordered
    __shared__ int    Idx[M_];
    __shared__ float  dinvS[8 * 32];

    const int t  = threadIdx.x;
    const int w  = t >> 6, l = t & 63;
    const int hi = l >> 5, ln = l & 31;
    const int* mi = member_idx + (((size_t)b * H_ + h) * K_ + kc) * M_;
    const ushort* slab = qkv + (size_t)bh * N_ * 96;
    const size_t rowbase = (size_t)b * N_;
    const float scale2 = 0.17677669529663687f * LOG2E;  // (C/H)^-0.5 * log2(e)

    // ---- early issue: Q fragment (regs)
    const int iq = 32 * w + ln;
    const int nq = mi[iq];
    bf16x8 qf = *(const bf16x8*)(slab + (size_t)nq * 96 + hi * 8);
    // ---- early issue: V rows to regs (pack deferred past softmax)
    const int u = t >> 2, cq = t & 3;
    const int n0 = mi[2 * u], n1 = mi[2 * u + 1];
    const ushort* s0 = slab + (size_t)n0 * 96 + 32 + cq * 16;
    const ushort* s1 = slab + (size_t)n1 * 96 + 32 + cq * 16;
    ushort8v v0a = *(const ushort8v*)s0;
    ushort8v v0b = *(const ushort8v*)(s0 + 8);
    ushort8v v1a = *(const ushort8v*)s1;
    ushort8v v1b = *(const ushort8v*)(s1 + 8);
    // ---- K stage via global_load_lds (per-lane gather source, linear LDS dest)
    {
        int row = t >> 1, half = t & 1;
        int n = mi[row];
        load_lds_16B(slab + (size_t)n * 96 + 16 + half * 8, &Ks[t * 8]);
    }
    // ---- bias + Idx (crow-reordered); overlaps in-flight loads
    if (t < M_) {
        int n = mi[t];
        Idx[t] = n;
        float inv0 = 1.f / __uint_as_float(pmax_u[0]);
        float inv1 = 1.f / __uint_as_float(pmax_u[1]);
        float sp = pos[(rowbase + n) * 2 + 0] * inv0 * w_pos[h * 2 + 0]
                 + pos[(rowbase + n) * 2 + 1] * inv1 * w_pos[h * 2 + 1];
        int jj = t & 31, jt = t >> 5;
        int r  = (jj & 3) | ((jj >> 3) << 2);
        int hb = (jj >> 2) & 1;
        SpA[jt * 32 + hb * 16 + r] = sp * LOG2E;
    }
    __syncthreads();

    // ---- QK^T: 8 j-tiles of 32x32
    f32x16 zero16;
    #pragma unroll
    for (int i = 0; i < 16; i++) zero16[i] = 0.f;
    f32x16 sac[8];
    __builtin_amdgcn_s_setprio(1);
    #pragma unroll
    for (int jt = 0; jt < 8; jt++) {
        bf16x8 kf = *(const bf16x8*)&Ks[(32 * jt + ln) * 16 + hi * 8];
        sac[jt] = __builtin_amdgcn_mfma_f32_32x32x16_bf16(kf, qf, zero16, 0, 0, 0);
    }
    __builtin_amdgcn_s_setprio(0);

    // ---- softmax in log2 domain (lane-local + one cross-half exchange)
    float mx = -3.0e38f;
    #pragma unroll
    for (int jt = 0; jt < 8; jt++) {
        f32x4 bia[4];
        #pragma unroll
        for (int q4 = 0; q4 < 4; q4++)
            bia[q4] = *(const f32x4*)&SpA[jt * 32 + hi * 16 + q4 * 4];
        #pragma unroll
        for (int r = 0; r < 16; r++)
            sac[jt][r] = fmaf(sac[jt][r], scale2, bia[r >> 2][r & 3]);
        #pragma unroll
        for (int r = 0; r < 16; r += 2)
            mx = fmaxf(mx, fmaxf(sac[jt][r], sac[jt][r + 1]));   // -> v_max3
    }
    mx = fmaxf(mx, __shfl_xor(mx, 32));
    float sum = 0.f;
    #pragma unroll
    for (int jt = 0; jt < 8; jt++)
        #pragma unroll
        for (int r = 0; r < 16; r++) {
            float p = exp2f(sac[jt][r] - mx);
            sac[jt][r] = p;
            sum += p;
        }
    sum += __shfl_xor(sum, 32);
    float inv = 1.f / sum;
    if (hi == 0) dinvS[w * 32 + ln] = inv;

    // ---- deferred V pack-transpose (regs long since landed)
    #pragma unroll
    for (int i = 0; i < 8; i++) {
        int c0 = cq * 16 + i, c1 = cq * 16 + 8 + i;
        *(unsigned*)&Vt[c0 * VSTR + 2 * u] = (unsigned)(ushort)v0a[i] | ((unsigned)(ushort)v1a[i] << 16);
        *(unsigned*)&Vt[c1 * VSTR + 2 * u] = (unsigned)(ushort)v0b[i] | ((unsigned)(ushort)v1b[i] << 16);
    }
    __syncthreads();

    // ---- PV: O[i][c] = sum_j P[j][i] V[j][c]; A-frag via cvt_pk+permlane
    f32x16 oa0 = zero16, oa1 = zero16;
    __builtin_amdgcn_s_setprio(1);
    #pragma unroll
    for (int g = 0; g < 16; g++) {
        const int jt = g >> 1, hf = (g & 1) * 8;
        unsigned a0 = cvtpk_bf16(sac[jt][hf + 0], sac[jt][hf + 1]);
        unsigned a1 = cvtpk_bf16(sac[jt][hf + 2], sac[jt][hf + 3]);
        unsigned b0 = cvtpk_bf16(sac[jt][hf + 4], sac[jt][hf + 5]);
        unsigned b1 = cvtpk_bf16(sac[jt][hf + 6], sac[jt][hf + 7]);
        asm("v_permlane32_swap_b32 %0, %1" : "+v"(a0), "+v"(b0));
        asm("v_permlane32_swap_b32 %0, %1" : "+v"(a1), "+v"(b1));
        union { unsigned uu[4]; bf16x8 v; } pa;
        pa.uu[0] = a0; pa.uu[1] = a1; pa.uu[2] = b0; pa.uu[3] = b1;
        union { ushort4v hv[2]; bf16x8 v; } vf0, vf1;
        vf0.hv[0] = *(const ushort4v*)&Vt[ln * VSTR + g * 16 + hi * 8];
        vf0.hv[1] = *(const ushort4v*)&Vt[ln * VSTR + g * 16 + hi * 8 + 4];
        vf1.hv[0] = *(const ushort4v*)&Vt[(ln + 32) * VSTR + g * 16 + hi * 8];
        vf1.hv[1] = *(const ushort4v*)&Vt[(ln + 32) * VSTR + g * 16 + hi * 8 + 4];
        oa0 = __builtin_amdgcn_mfma_f32_32x32x16_bf16(pa.v, vf0.v, oa0, 0, 0, 0);
        oa1 = __builtin_amdgcn_mfma_f32_32x32x16_bf16(pa.v, vf1.v, oa1, 0, 0, 0);
    }
    __builtin_amdgcn_s_setprio(0);

    // ---- epilogue -> feat2 slab [bh][n][64]
    ushort* f2slab = feat2 + (size_t)bh * N_ * 64;
    #pragma unroll
    for (int r = 0; r < 16; r++) {
        int crow = (r & 3) + 8 * (r >> 2) + 4 * hi;
        float dv = dinvS[w * 32 + crow];
        int ni = Idx[32 * w + crow];
        __hip_bfloat16 o0 = __float2bfloat16(oa0[r] * dv);
        __hip_bfloat16 o1 = __float2bfloat16(oa1[r] * dv);
        ushort* dst = f2slab + (size_t)ni * 64 + ln;
        dst[0]  = *(const ushort*)&o0;
        dst[32] = *(const ushort*)&o1;
    }
}

// ---------------------------------------------------------------- proj GEMM
// A = feat2 slabs [bh][n][64]; K-block 64 == one head chunk, so staging stays
// contiguous: addr((row,k)) = ((b*12 + k/64)*N + n)*64 + k%64. Out f32 [row][384].
__global__ __launch_bounds__(256) void gemm_proj_s(const ushort* __restrict__ A,
                                                   const ushort* __restrict__ Bw,
                                                   const float* __restrict__ bias,
                                                   float* __restrict__ Cout) {
    constexpr int NB = C_ / 128;              // 3 column blocks
    __shared__ ushort As[128 * 64];
    __shared__ ushort Bs[128 * 64];
    const int wgid = blockIdx.x;
    const int xcd  = wgid & 7;
    const int loc  = wgid >> 3;
    const int bm = (xcd * 32 + loc / NB) * 128;
    const int bn = (loc % NB) * 128;
    const int t = threadIdx.x;
    const int l = t & 63;
    const int wr = (t >> 6) >> 1, wc = (t >> 6) & 1;
    const int fr = l & 15, fq = l >> 4;
    const int bq = bm >> 13;                  // batch
    const int nbase = bm & (N_ - 1);

    f32x4 zero = {0.f, 0.f, 0.f, 0.f};
    f32x4 acc[4][4];
    #pragma unroll
    for (int m = 0; m < 4; m++)
        #pragma unroll
        for (int n = 0; n < 4; n++) acc[m][n] = zero;

    for (int k0 = 0; k0 < 768; k0 += 64) {
        const ushort* Aslab = A + ((size_t)(bq * H_ + (k0 >> 6)) * N_ + nbase) * 64;
        #pragma unroll
        for (int i = 0; i < 4; i++) {
            int elem = (i * 256 + t) * 8;
            int row = elem >> 6, kk = elem & 63;
            int kks = kk ^ ((row & 7) << 3);
            load_lds_16B(Aslab + (size_t)row * 64 + kks, &As[elem]);
        }
        #pragma unroll
        for (int i = 0; i < 4; i++) {
            int elem = (i * 256 + t) * 8;
            int row = elem >> 6, kk = elem & 63;
            int kks = kk ^ ((row & 7) << 3);
            load_lds_16B(Bw + (size_t)(bn + row) * 768 + k0 + kks, &Bs[elem]);
        }
        __syncthreads();
        #pragma unroll
        for (int kk = 0; kk < 64; kk += 32) {
            bf16x8 af[4], bfr[4];
            #pragma unroll
            for (int m = 0; m < 4; m++) {
                int row = wr * 64 + m * 16 + fr;
                af[m] = *reinterpret_cast<const bf16x8*>(&As[row * 64 + ((kk + fq * 8) ^ ((row & 7) << 3))]);
            }
            #pragma unroll
            for (int n = 0; n < 4; n++) {
                int row = wc * 64 + n * 16 + fr;
                bfr[n] = *reinterpret_cast<const bf16x8*>(&Bs[row * 64 + ((kk + fq * 8) ^ ((row & 7) << 3))]);
            }
            #pragma unroll
            for (int m = 0; m < 4; m++)
                #pragma unroll
                for (int n = 0; n < 4; n++)
                    acc[m][n] = __builtin_amdgcn_mfma_f32_16x16x32_bf16(af[m], bfr[n], acc[m][n], 0, 0, 0);
        }
        __syncthreads();
    }
    #pragma unroll
    for (int n = 0; n < 4; n++) {
        int col = bn + wc * 64 + n * 16 + fr;
        float bc = bias[col];
        #pragma unroll
        for (int m = 0; m < 4; m++) {
            #pragma unroll
            for (int r = 0; r < 4; r++) {
                size_t row = bm + wr * 64 + m * 16 + fq * 4 + r;
                Cout[row * C_ + col] = acc[m][n][r] + bc;
            }
        }
    }
}

// ---------------------------------------------------------------- launch
extern "C" void kernel_launch(void* const* d_in, const int* in_sizes, int n_in,
                              void* d_out, int out_size, void* d_ws, size_t ws_size,
                              hipStream_t stream) {
    const float* pos    = (const float*)d_in[0];
    const float* feat   = (const float*)d_in[1];
    const int*   midx   = (const int*)  d_in[2];
    const float* w_qkv  = (const float*)d_in[3];
    const float* b_qkv  = (const float*)d_in[4];
    const float* w_pos  = (const float*)d_in[5];
    const float* b_pos  = (const float*)d_in[6];  (void)b_pos; // cancels in softmax
    const float* w_proj = (const float*)d_in[7];
    const float* b_proj = (const float*)d_in[8];
    float* out = (float*)d_out;

    // workspace (126.4 MB, r5-proven):
    // [pmax 256B | qkv 75.5MB | wproj 0.59MB | REGION: {featb 25.2 + wqkvb 0.88} -> feat2 50.3]
    char* ws = (char*)d_ws;
    unsigned* pmax  = (unsigned*)ws;
    ushort*   qkv   = (ushort*)(ws + 256);
    ushort*   wproj = (ushort*)(ws + 256 + 75497472);
    char*     region = ws + 256 + 75497472 + 589824;
    ushort*   featb = (ushort*)region;
    ushort*   wqkvb = (ushort*)(region + 25165824);
    ushort*   feat2 = (ushort*)region;   // overwrites featb/wqkvb after gemm_qkv_s

    hipMemsetAsync(pmax, 0, 8, stream);  // ws is NOT re-poisoned between replays
    posmax_kernel<<<64, 256, 0, stream>>>(pos, pmax);
    cast_kernel<<<(BN_ * C_ / 4 + 255) / 256, 256, 0, stream>>>(feat, featb, BN_ * C_ / 4);
    cast_w<<<(WQN + WPN) / 256, 256, 0, stream>>>(w_qkv, w_proj, wqkvb, wproj);
    gemm_qkv_s<<<8 * 32 * (QKVD / 128), 256, 0, stream>>>(featb, wqkvb, b_qkv, qkv);
    attn_kernel<<<6 * 256, 512, 0, stream>>>(qkv, midx, pos, w_pos, pmax, feat2);
    gemm_proj_s<<<8 * 32 * (C_ / 128), 256, 0, stream>>>(feat2, wproj, b_proj, out);
}